// Round 10
// baseline (228.739 us; speedup 1.0000x reference)
//
#include <hip/hip_runtime.h>

// NNGLS: y_decor, o_decor, o for N=200000, M=20, MLP 64->256->1.
//
// ROUND-10 STRUCTURE: b_i / f_i depend only on pos/nbr/theta -- independent
// of the MLP. So:
//  K1 (fused_kernel): heterogeneous blocks, one launch.
//     * mlp blocks (blockIdx%3==1): r7 MFMA body verbatim (2 M-tiles/wave,
//       b1/w2 via LDS) -> writes o.
//     * solve blocks: build + eliminate the bordered 21x21 (r7 quad-split,
//       5 rolled phases, switch literal copies, literal ds_swizzle) with the
//       BORDER VECTOR REMOVED (-420 FMA/lane). Then back-substitute
//       U b = L^{-1}c in 20 straight-line literal steps: eliminated csx IS U
//       (rows freeze after their pivot step: mall[r<=k]=0), C20-final IS
//       L^{-1}c. Store wis = {b_j*is (j<20), is} at stride 24 in d_ws.
//     MFMA-heavy and VALU-heavy blocks co-resident per CU (m114: pipes
//     overlap) -> expected max(mlp, solve) instead of sum.
//  K2 (epilogue_kernel): yd[i] = is*y_i - sum wis_j*y[idx_j]; od same with o.
//     y/o are 800KB each -> L2-resident gathers; ~10us.
// r9 lesson kept: replicated C20 (distribution added swizzles to the serial
// critical path: VALUBusy 49->38, dur 82->103 -> reverted).
// Residency rules kept: one function scope per array, rolled loops + switch
// literal copies, (256,2) cap only.

#define MM   20
#define PP   64
#define HH   256
#define EPSF 1e-12f
#define WSTR 24   // workspace stride per node (floats)

// quad-split storage: slot j (col 4j+h), rows 0..4j+3 at offset 2j(j+1);
// replicated col 20 at offset 60.
#define CSE(j, r) csx[2*(j)*((j)+1) + (r)]
#define C20(r)    csx[60 + (r)]

typedef __attribute__((ext_vector_type(8))) short bf16x8;
typedef __attribute__((ext_vector_type(4))) float f32x4;

static __device__ __forceinline__ unsigned short f2bf(float f) {
    unsigned int u = __builtin_bit_cast(unsigned int, f);
    u += 0x7fffu + ((u >> 16) & 1u);          // RNE
    return (unsigned short)(u >> 16);
}
static __device__ __forceinline__ float bf2f(unsigned short h) {
    unsigned int u = ((unsigned int)h) << 16;
    return __builtin_bit_cast(float, u);
}

// quad lane-select swizzle, literal 8-bit pattern (2 bits per lane)
#define QSWZ(v, pat) __builtin_bit_cast(float, __builtin_amdgcn_ds_swizzle( \
    __builtin_bit_cast(int, (v)), 0x8000 | (pat)))

// gather m[r]=a[k][r]*rp from the owner of column r (lane r&3, slot r>>2)
#define GATH(R) mall[R] = QSWZ(mv[(R) >> 2], 0x55 * ((R) & 3));

// case K of phase P: copy pivot-row data (literal indices), broadcast pivot
#define SCASE(K, P) case K: {                                              \
    _Pragma("unroll")                                                      \
    for (int j = (P); j < 5; ++j) pk[j] = CSE(j, (K));                     \
    p20 = C20(K);                                                          \
    pd  = QSWZ(pk[(P)], 0x55 * ((K) & 3));                                 \
} break;

// back-substitution step R (straight-line, all indices literal).
// acc = sum over owned s>R of U[R][s]*b[s]; quad-reduce; divide by U[R][R].
#define BSTEP(R, JMIN) {                                                   \
    float acc = 0.0f;                                                      \
    _Pragma("unroll")                                                      \
    for (int j = (JMIN); j < 5; ++j) {                                     \
        float t = CSE(j, (R)) * bl[j];                                     \
        acc += (4*j + h_ > (R)) ? t : 0.0f;                                \
    }                                                                      \
    acc += __shfl_xor(acc, 1, 64);                                         \
    acc += __shfl_xor(acc, 2, 64);                                         \
    float pdr = QSWZ(CSE((R) >> 2, (R)), 0x55 * ((R) & 3));                \
    float rr = __builtin_amdgcn_rcpf(pdr);                                 \
    rr = rr * (2.0f - pdr * rr);                                           \
    float bR = (C20(R) - acc) * rr;                                        \
    if (((R) & 3) == h_) bl[(R) >> 2] = bR;                                \
}

__global__ __launch_bounds__(256, 2)
void fused_kernel(const float* __restrict__ x,
                  const float* __restrict__ w1,
                  const float* __restrict__ b1,
                  const float* __restrict__ w2,
                  const float* __restrict__ b2,
                  const float* __restrict__ pos,
                  const int*   __restrict__ nbr,
                  const float* __restrict__ theta,
                  float* __restrict__ o_out,
                  float* __restrict__ wis,
                  int n, int nm)
{
    __shared__ __align__(16) short swh[PP * HH];   // 32 KB  w1 hi, frag order
    __shared__ __align__(16) short swl[PP * HH];   // 32 KB  w1 lo
    __shared__ float sb1[HH];                      // 1 KB
    __shared__ float sw2[HH];                      // 1 KB

    const int b   = blockIdx.x;
    const int grp = b / 3;
    const int rem = b - grp * 3;
    const int tid = threadIdx.x;

    if (rem == 1 && grp < nm) {
        // ================= MLP block (tile = grp) =================
        {
            const int col = tid;                       // 256 cols
            const int t = col >> 4, nn = col & 15;
            #pragma unroll
            for (int g = 0; g < 8; ++g) {              // k = g*8 + u
                const int s = g >> 2, q = g & 3;
                bf16x8 hv, lv;
                #pragma unroll
                for (int u = 0; u < 8; ++u) {
                    float v = w1[(g * 8 + u) * HH + col];
                    unsigned short h = f2bf(v);
                    hv[u] = (short)h;
                    lv[u] = (short)f2bf(v - bf2f(h));
                }
                const int base = ((((t * 2 + s) * 4 + q) * 16) + nn) * 8;
                *(bf16x8*)&swh[base] = hv;
                *(bf16x8*)&swl[base] = lv;
            }
            sb1[tid] = b1[tid];
            sw2[tid] = w2[tid];
        }
        __syncthreads();

        const int lane = tid & 63;
        const int wv   = tid >> 6;
        const int nn   = lane & 15;
        const int q    = lane >> 4;
        const int wb   = grp * 128 + wv * 32;

        bf16x8 ah[2][2], al[2][2];
        #pragma unroll
        for (int mt = 0; mt < 2; ++mt) {
            const int row = wb + mt * 16 + nn;
            #pragma unroll
            for (int s = 0; s < 2; ++s) {
                float v[8];
                if (row < n) {
                    const float* xp = x + (size_t)row * PP + s * 32 + q * 8;
                    float4 va = *(const float4*)(xp);
                    float4 vb = *(const float4*)(xp + 4);
                    v[0]=va.x; v[1]=va.y; v[2]=va.z; v[3]=va.w;
                    v[4]=vb.x; v[5]=vb.y; v[6]=vb.z; v[7]=vb.w;
                } else {
                    #pragma unroll
                    for (int u = 0; u < 8; ++u) v[u] = 0.0f;
                }
                bf16x8 h, l;
                #pragma unroll
                for (int u = 0; u < 8; ++u) {
                    unsigned short hb = f2bf(v[u]);
                    h[u] = (short)hb;
                    l[u] = (short)f2bf(v[u] - bf2f(hb));
                }
                ah[mt][s] = h;
                al[mt][s] = l;
            }
        }

        float part[2][4];
        #pragma unroll
        for (int mt = 0; mt < 2; ++mt)
            #pragma unroll
            for (int r = 0; r < 4; ++r) part[mt][r] = 0.0f;

        #pragma unroll
        for (int t = 0; t < 16; ++t) {
            f32x4 acc[2];
            #pragma unroll
            for (int mt = 0; mt < 2; ++mt) acc[mt] = (f32x4)(0.0f);
            #pragma unroll
            for (int s = 0; s < 2; ++s) {
                const int fb = ((((t * 2 + s) * 4 + q) * 16) + nn) * 8;
                bf16x8 bh = *(const bf16x8*)&swh[fb];
                bf16x8 bl2 = *(const bf16x8*)&swl[fb];
                #pragma unroll
                for (int mt = 0; mt < 2; ++mt) {
                    acc[mt] = __builtin_amdgcn_mfma_f32_16x16x32_bf16(ah[mt][s], bh,  acc[mt], 0, 0, 0);
                    acc[mt] = __builtin_amdgcn_mfma_f32_16x16x32_bf16(al[mt][s], bh,  acc[mt], 0, 0, 0);
                    acc[mt] = __builtin_amdgcn_mfma_f32_16x16x32_bf16(ah[mt][s], bl2, acc[mt], 0, 0, 0);
                }
            }
            const float b1t = sb1[t * 16 + nn];
            const float w2t = sw2[t * 16 + nn];
            #pragma unroll
            for (int mt = 0; mt < 2; ++mt)
                #pragma unroll
                for (int r = 0; r < 4; ++r)
                    part[mt][r] = fmaf(fmaxf(acc[mt][r] + b1t, 0.0f), w2t, part[mt][r]);
        }

        #pragma unroll
        for (int w = 1; w < 16; w <<= 1)
            #pragma unroll
            for (int mt = 0; mt < 2; ++mt)
                #pragma unroll
                for (int r = 0; r < 4; ++r)
                    part[mt][r] += __shfl_xor(part[mt][r], w, 64);

        const float bb = b2[0];
        if (nn == 0) {
            #pragma unroll
            for (int mt = 0; mt < 2; ++mt) {
                const int row = wb + mt * 16 + q * 4;
                if (row < n) {
                    float4 o4 = make_float4(part[mt][0] + bb, part[mt][1] + bb,
                                            part[mt][2] + bb, part[mt][3] + bb);
                    *(float4*)&o_out[row] = o4;
                }
            }
        }
        return;
    }

    // ================= SOLVE block =================
    {
        int mcnt = (b + 1) / 3; if (mcnt > nm) mcnt = nm;
        const int sidx = b - mcnt;
        const int h_   = tid & 3;
        const int i    = sidx * 64 + (tid >> 2);
        if (i >= n) return;

        const float sigma_sq = theta[0];
        const float phi      = theta[1];
        const float tau      = theta[2];
        const float tau_sq   = tau * sigma_sq;

        const float L2E = 1.44269504088896340736f;
        const float c1  = -phi * L2E;
        const float c0  = __builtin_amdgcn_logf(sigma_sq);

        const float sqrtEPS = __builtin_amdgcn_sqrtf(EPSF);
        const float diagA   = __builtin_amdgcn_exp2f(fmaf(sqrtEPS, c1, c0)) + tau_sq;
        const float diagB   = sigma_sq + tau;

        int idx[MM];
        const int4* nb4 = (const int4*)(nbr + (size_t)i * MM);
        #pragma unroll
        for (int k = 0; k < MM / 4; ++k) {
            int4 v = nb4[k];
            idx[4*k] = v.x; idx[4*k+1] = v.y; idx[4*k+2] = v.z; idx[4*k+3] = v.w;
        }

        float px[21], py[21];
        const float2* pos2 = (const float2*)pos;
        #pragma unroll
        for (int j = 0; j < MM; ++j) {
            float2 p = pos2[idx[j]];
            px[j] = p.x; py[j] = p.y;
        }
        {
            float2 p = pos2[i];
            px[20] = p.x; py[20] = p.y;
        }

        float cx[5], cy[5];
        #pragma unroll
        for (int j = 0; j < 5; ++j) {
            int cj = nbr[(size_t)i * MM + 4*j + h_];
            float2 p = pos2[cj];
            cx[j] = p.x; cy[j] = p.y;
        }

        // ---- build my slots + replicated col 20 ----
        float csx[81];
        #pragma unroll
        for (int j = 0; j < 5; ++j) {
            #pragma unroll
            for (int r = 0; r <= 4*j + 3; ++r) {
                float dx = px[r] - cx[j];
                float dy = py[r] - cy[j];
                float d  = __builtin_amdgcn_sqrtf(fmaf(dx, dx, fmaf(dy, dy, EPSF)));
                float v  = __builtin_amdgcn_exp2f(fmaf(d, c1, c0));
                v = (r == 4*j + h_) ? diagA : v;
                CSE(j, r) = v;
            }
        }
        #pragma unroll
        for (int r = 0; r < 20; ++r) {
            float dx = px[r] - px[20];
            float dy = py[r] - py[20];
            float d  = __builtin_amdgcn_sqrtf(fmaf(dx, dx, fmaf(dy, dy, EPSF)));
            C20(r)   = __builtin_amdgcn_exp2f(fmaf(d, c1, c0));
        }
        C20(20) = diagB;

        // ---- elimination: 5 phases x 4 rolled steps (no border vector) ----
        float pk[5], mv[5], mall[21], p20, pd;

        #pragma unroll 1
        for (int k = 0; k < 4; ++k) {
            switch (k) {
            SCASE(0,0) SCASE(1,0) SCASE(2,0) SCASE(3,0)
            default: break;
            }
            float rp = __builtin_amdgcn_rcpf(pd);
            rp = rp * (2.0f - pd * rp);
            #pragma unroll
            for (int j = 0; j < 5; ++j)
                mv[j] = (4*j + h_ > k) ? pk[j] * rp : 0.0f;
            GATH(0)  GATH(1)  GATH(2)  GATH(3)  GATH(4)  GATH(5)  GATH(6)
            GATH(7)  GATH(8)  GATH(9)  GATH(10) GATH(11) GATH(12) GATH(13)
            GATH(14) GATH(15) GATH(16) GATH(17) GATH(18) GATH(19)
            mall[20] = p20 * rp;
            #pragma unroll
            for (int j = 0; j < 5; ++j) {
                float pkj = pk[j];
                #pragma unroll
                for (int r = 0; r <= 4*j + 3; ++r)
                    CSE(j, r) = fmaf(-mall[r], pkj, CSE(j, r));
            }
            #pragma unroll
            for (int r = 0; r <= 20; ++r)
                C20(r) = fmaf(-mall[r], p20, C20(r));
        }

        #pragma unroll 1
        for (int k = 4; k < 8; ++k) {
            switch (k) {
            SCASE(4,1) SCASE(5,1) SCASE(6,1) SCASE(7,1)
            default: break;
            }
            float rp = __builtin_amdgcn_rcpf(pd);
            rp = rp * (2.0f - pd * rp);
            #pragma unroll
            for (int j = 1; j < 5; ++j)
                mv[j] = (4*j + h_ > k) ? pk[j] * rp : 0.0f;
            GATH(4)  GATH(5)  GATH(6)  GATH(7)  GATH(8)  GATH(9)  GATH(10)
            GATH(11) GATH(12) GATH(13) GATH(14) GATH(15) GATH(16) GATH(17)
            GATH(18) GATH(19)
            mall[20] = p20 * rp;
            #pragma unroll
            for (int j = 1; j < 5; ++j) {
                float pkj = pk[j];
                #pragma unroll
                for (int r = 4; r <= 4*j + 3; ++r)
                    CSE(j, r) = fmaf(-mall[r], pkj, CSE(j, r));
            }
            #pragma unroll
            for (int r = 4; r <= 20; ++r)
                C20(r) = fmaf(-mall[r], p20, C20(r));
        }

        #pragma unroll 1
        for (int k = 8; k < 12; ++k) {
            switch (k) {
            SCASE(8,2) SCASE(9,2) SCASE(10,2) SCASE(11,2)
            default: break;
            }
            float rp = __builtin_amdgcn_rcpf(pd);
            rp = rp * (2.0f - pd * rp);
            #pragma unroll
            for (int j = 2; j < 5; ++j)
                mv[j] = (4*j + h_ > k) ? pk[j] * rp : 0.0f;
            GATH(8)  GATH(9)  GATH(10) GATH(11) GATH(12) GATH(13) GATH(14)
            GATH(15) GATH(16) GATH(17) GATH(18) GATH(19)
            mall[20] = p20 * rp;
            #pragma unroll
            for (int j = 2; j < 5; ++j) {
                float pkj = pk[j];
                #pragma unroll
                for (int r = 8; r <= 4*j + 3; ++r)
                    CSE(j, r) = fmaf(-mall[r], pkj, CSE(j, r));
            }
            #pragma unroll
            for (int r = 8; r <= 20; ++r)
                C20(r) = fmaf(-mall[r], p20, C20(r));
        }

        #pragma unroll 1
        for (int k = 12; k < 16; ++k) {
            switch (k) {
            SCASE(12,3) SCASE(13,3) SCASE(14,3) SCASE(15,3)
            default: break;
            }
            float rp = __builtin_amdgcn_rcpf(pd);
            rp = rp * (2.0f - pd * rp);
            #pragma unroll
            for (int j = 3; j < 5; ++j)
                mv[j] = (4*j + h_ > k) ? pk[j] * rp : 0.0f;
            GATH(12) GATH(13) GATH(14) GATH(15) GATH(16) GATH(17) GATH(18)
            GATH(19)
            mall[20] = p20 * rp;
            #pragma unroll
            for (int j = 3; j < 5; ++j) {
                float pkj = pk[j];
                #pragma unroll
                for (int r = 12; r <= 4*j + 3; ++r)
                    CSE(j, r) = fmaf(-mall[r], pkj, CSE(j, r));
            }
            #pragma unroll
            for (int r = 12; r <= 20; ++r)
                C20(r) = fmaf(-mall[r], p20, C20(r));
        }

        #pragma unroll 1
        for (int k = 16; k < 20; ++k) {
            switch (k) {
            SCASE(16,4) SCASE(17,4) SCASE(18,4) SCASE(19,4)
            default: break;
            }
            float rp = __builtin_amdgcn_rcpf(pd);
            rp = rp * (2.0f - pd * rp);
            mv[4] = (16 + h_ > k) ? pk[4] * rp : 0.0f;
            GATH(16) GATH(17) GATH(18) GATH(19)
            mall[20] = p20 * rp;
            {
                float pkj = pk[4];
                #pragma unroll
                for (int r = 16; r <= 19; ++r)
                    CSE(4, r) = fmaf(-mall[r], pkj, CSE(4, r));
            }
            #pragma unroll
            for (int r = 16; r <= 20; ++r)
                C20(r) = fmaf(-mall[r], p20, C20(r));
        }

        // ---- back-substitution: U b = L^{-1}c, 20 straight-line steps ----
        // (rows of csx/C20 froze after their pivot step; csx IS U, C20 IS rhs)
        float bl[5];
        BSTEP(19,5) BSTEP(18,4) BSTEP(17,4) BSTEP(16,4)
        BSTEP(15,4) BSTEP(14,3) BSTEP(13,3) BSTEP(12,3)
        BSTEP(11,3) BSTEP(10,2) BSTEP(9,2)  BSTEP(8,2)
        BSTEP(7,2)  BSTEP(6,1)  BSTEP(5,1)  BSTEP(4,1)
        BSTEP(3,1)  BSTEP(2,0)  BSTEP(1,0)  BSTEP(0,0)

        // ---- f, is, store weights ----
        float f  = C20(20);
        float is = __builtin_amdgcn_rsqf(f);
        is = is * fmaf(-0.5f * f * is, is, 1.5f);

        float* wp = wis + (size_t)i * WSTR;
        #pragma unroll
        for (int j = 0; j < 5; ++j)
            wp[4*j + h_] = bl[j] * is;
        if (h_ == 0) wp[20] = is;
    }
}

__global__ __launch_bounds__(256, 4)
void epilogue_kernel(const int*   __restrict__ nbr,
                     const float* __restrict__ y,
                     const float* __restrict__ o_in,
                     const float* __restrict__ wis,
                     float* __restrict__ yd,
                     float* __restrict__ od, int n)
{
    const int i = blockIdx.x * 256 + threadIdx.x;
    if (i >= n) return;

    float wv_[20];
    {
        const float4* w4 = (const float4*)(wis + (size_t)i * WSTR);
        *(float4*)&wv_[0]  = w4[0];
        *(float4*)&wv_[4]  = w4[1];
        *(float4*)&wv_[8]  = w4[2];
        *(float4*)&wv_[12] = w4[3];
        *(float4*)&wv_[16] = w4[4];
    }
    const float is = wis[(size_t)i * WSTR + 20];

    int idx[MM];
    const int4* nb4 = (const int4*)(nbr + (size_t)i * MM);
    #pragma unroll
    for (int k = 0; k < MM / 4; ++k) {
        int4 v = nb4[k];
        idx[4*k] = v.x; idx[4*k+1] = v.y; idx[4*k+2] = v.z; idx[4*k+3] = v.w;
    }

    float sy = 0.0f, so = 0.0f;
    #pragma unroll
    for (int j = 0; j < MM; ++j) {
        sy = fmaf(wv_[j], y[idx[j]],    sy);
        so = fmaf(wv_[j], o_in[idx[j]], so);
    }
    yd[i] = fmaf(is, y[i],    -sy);
    od[i] = fmaf(is, o_in[i], -so);
}

extern "C" void kernel_launch(void* const* d_in, const int* in_sizes, int n_in,
                              void* d_out, int out_size, void* d_ws, size_t ws_size,
                              hipStream_t stream)
{
    const float* x     = (const float*)d_in[0];
    const float* pos   = (const float*)d_in[1];
    const float* y     = (const float*)d_in[2];
    const int*   nbr   = (const int*)  d_in[3];
    const float* theta = (const float*)d_in[4];
    const float* w1    = (const float*)d_in[5];
    const float* b1    = (const float*)d_in[6];
    const float* w2    = (const float*)d_in[7];
    const float* b2    = (const float*)d_in[8];

    const int n = in_sizes[2];                 // N
    float* out = (float*)d_out;
    float* yd = out;
    float* od = out + (size_t)n;
    float* oo = out + 2 * (size_t)n;
    float* wis = (float*)d_ws;                 // n * 24 floats = 19.2 MB

    const int nm = (n + 127) / 128;            // mlp blocks (128 nodes each)
    const int ns = (n + 63) / 64;              // solve blocks (64 nodes each)
    fused_kernel<<<nm + ns, 256, 0, stream>>>(x, w1, b1, w2, b2,
                                              pos, nbr, theta, oo, wis, n, nm);
    epilogue_kernel<<<(n + 255) / 256, 256, 0, stream>>>(nbr, y, oo, wis,
                                                         yd, od, n);
}

// Round 11
// 218.613 us; speedup vs baseline: 1.0463x; 1.0463x over previous
//
#include <hip/hip_runtime.h>

// NNGLS: y_decor, o_decor, o for N=200000, M=20, MLP 64->256->1.
//
// ROUND-11: keep r10's fused heterogeneous kernel (mlp MFMA blocks + solve
// blocks co-resident; proven overlap: MfmaUtil 7.5% AND VALUBusy 51%, fused
// 110us vs 157us serial) and kill the 80us epilogue:
//   * yd is computed INSIDE solve blocks (depends only on input y): after
//     back-substitution, each lane gathers y for its 5 owned columns, dots
//     with bl[], 2 quad-swizzle reduces, lane0 writes yd.
//   * epilogue handles od ONLY, QUAD-PARALLEL: 4 lanes/node, 5 wis + 5 o
//     gathers per lane + 2 shfl_xor (r10: 40 serial divergent gathers/thread
//     -- the measured ~80us was that dependent VMEM chain).
// All r5-r10 residency rules kept: arrays in one function scope, rolled
// `#pragma unroll 1` loops + switch literal copies, literal-pattern
// ds_swizzle, (256,2) cap for the big-array kernel.

#define MM   20
#define PP   64
#define HH   256
#define EPSF 1e-12f
#define WSTR 24   // workspace stride per node (floats)

// quad-split storage: slot j (col 4j+h), rows 0..4j+3 at offset 2j(j+1);
// replicated col 20 at offset 60.
#define CSE(j, r) csx[2*(j)*((j)+1) + (r)]
#define C20(r)    csx[60 + (r)]

typedef __attribute__((ext_vector_type(8))) short bf16x8;
typedef __attribute__((ext_vector_type(4))) float f32x4;

static __device__ __forceinline__ unsigned short f2bf(float f) {
    unsigned int u = __builtin_bit_cast(unsigned int, f);
    u += 0x7fffu + ((u >> 16) & 1u);          // RNE
    return (unsigned short)(u >> 16);
}
static __device__ __forceinline__ float bf2f(unsigned short h) {
    unsigned int u = ((unsigned int)h) << 16;
    return __builtin_bit_cast(float, u);
}

// quad lane-select swizzle, literal 8-bit pattern (2 bits per lane)
#define QSWZ(v, pat) __builtin_bit_cast(float, __builtin_amdgcn_ds_swizzle( \
    __builtin_bit_cast(int, (v)), 0x8000 | (pat)))

// gather m[r]=a[k][r]*rp from the owner of column r (lane r&3, slot r>>2)
#define GATH(R) mall[R] = QSWZ(mv[(R) >> 2], 0x55 * ((R) & 3));

// case K of phase P: copy pivot-row data (literal indices), broadcast pivot
#define SCASE(K, P) case K: {                                              \
    _Pragma("unroll")                                                      \
    for (int j = (P); j < 5; ++j) pk[j] = CSE(j, (K));                     \
    p20 = C20(K);                                                          \
    pd  = QSWZ(pk[(P)], 0x55 * ((K) & 3));                                 \
} break;

// back-substitution step R (straight-line, all indices literal).
#define BSTEP(R, JMIN) {                                                   \
    float acc = 0.0f;                                                      \
    _Pragma("unroll")                                                      \
    for (int j = (JMIN); j < 5; ++j) {                                     \
        float t = CSE(j, (R)) * bl[j];                                     \
        acc += (4*j + h_ > (R)) ? t : 0.0f;                                \
    }                                                                      \
    acc += __shfl_xor(acc, 1, 64);                                         \
    acc += __shfl_xor(acc, 2, 64);                                         \
    float pdr = QSWZ(CSE((R) >> 2, (R)), 0x55 * ((R) & 3));                \
    float rr = __builtin_amdgcn_rcpf(pdr);                                 \
    rr = rr * (2.0f - pdr * rr);                                           \
    float bR = (C20(R) - acc) * rr;                                        \
    if (((R) & 3) == h_) bl[(R) >> 2] = bR;                                \
}

__global__ __launch_bounds__(256, 2)
void fused_kernel(const float* __restrict__ x,
                  const float* __restrict__ w1,
                  const float* __restrict__ b1,
                  const float* __restrict__ w2,
                  const float* __restrict__ b2,
                  const float* __restrict__ pos,
                  const int*   __restrict__ nbr,
                  const float* __restrict__ theta,
                  const float* __restrict__ y,
                  float* __restrict__ o_out,
                  float* __restrict__ wis,
                  float* __restrict__ yd,
                  int n, int nm)
{
    __shared__ __align__(16) short swh[PP * HH];   // 32 KB  w1 hi, frag order
    __shared__ __align__(16) short swl[PP * HH];   // 32 KB  w1 lo
    __shared__ float sb1[HH];                      // 1 KB
    __shared__ float sw2[HH];                      // 1 KB

    const int b   = blockIdx.x;
    const int grp = b / 3;
    const int rem = b - grp * 3;
    const int tid = threadIdx.x;

    if (rem == 1 && grp < nm) {
        // ================= MLP block (tile = grp) =================
        {
            const int col = tid;                       // 256 cols
            const int t = col >> 4, nn = col & 15;
            #pragma unroll
            for (int g = 0; g < 8; ++g) {              // k = g*8 + u
                const int s = g >> 2, q = g & 3;
                bf16x8 hv, lv;
                #pragma unroll
                for (int u = 0; u < 8; ++u) {
                    float v = w1[(g * 8 + u) * HH + col];
                    unsigned short h = f2bf(v);
                    hv[u] = (short)h;
                    lv[u] = (short)f2bf(v - bf2f(h));
                }
                const int base = ((((t * 2 + s) * 4 + q) * 16) + nn) * 8;
                *(bf16x8*)&swh[base] = hv;
                *(bf16x8*)&swl[base] = lv;
            }
            sb1[tid] = b1[tid];
            sw2[tid] = w2[tid];
        }
        __syncthreads();

        const int lane = tid & 63;
        const int wv   = tid >> 6;
        const int nn   = lane & 15;
        const int q    = lane >> 4;
        const int wb   = grp * 128 + wv * 32;

        bf16x8 ah[2][2], al[2][2];
        #pragma unroll
        for (int mt = 0; mt < 2; ++mt) {
            const int row = wb + mt * 16 + nn;
            #pragma unroll
            for (int s = 0; s < 2; ++s) {
                float v[8];
                if (row < n) {
                    const float* xp = x + (size_t)row * PP + s * 32 + q * 8;
                    float4 va = *(const float4*)(xp);
                    float4 vb = *(const float4*)(xp + 4);
                    v[0]=va.x; v[1]=va.y; v[2]=va.z; v[3]=va.w;
                    v[4]=vb.x; v[5]=vb.y; v[6]=vb.z; v[7]=vb.w;
                } else {
                    #pragma unroll
                    for (int u = 0; u < 8; ++u) v[u] = 0.0f;
                }
                bf16x8 h, l;
                #pragma unroll
                for (int u = 0; u < 8; ++u) {
                    unsigned short hb = f2bf(v[u]);
                    h[u] = (short)hb;
                    l[u] = (short)f2bf(v[u] - bf2f(hb));
                }
                ah[mt][s] = h;
                al[mt][s] = l;
            }
        }

        float part[2][4];
        #pragma unroll
        for (int mt = 0; mt < 2; ++mt)
            #pragma unroll
            for (int r = 0; r < 4; ++r) part[mt][r] = 0.0f;

        #pragma unroll
        for (int t = 0; t < 16; ++t) {
            f32x4 acc[2];
            #pragma unroll
            for (int mt = 0; mt < 2; ++mt) acc[mt] = (f32x4)(0.0f);
            #pragma unroll
            for (int s = 0; s < 2; ++s) {
                const int fb = ((((t * 2 + s) * 4 + q) * 16) + nn) * 8;
                bf16x8 bh  = *(const bf16x8*)&swh[fb];
                bf16x8 bl2 = *(const bf16x8*)&swl[fb];
                #pragma unroll
                for (int mt = 0; mt < 2; ++mt) {
                    acc[mt] = __builtin_amdgcn_mfma_f32_16x16x32_bf16(ah[mt][s], bh,  acc[mt], 0, 0, 0);
                    acc[mt] = __builtin_amdgcn_mfma_f32_16x16x32_bf16(al[mt][s], bh,  acc[mt], 0, 0, 0);
                    acc[mt] = __builtin_amdgcn_mfma_f32_16x16x32_bf16(ah[mt][s], bl2, acc[mt], 0, 0, 0);
                }
            }
            const float b1t = sb1[t * 16 + nn];
            const float w2t = sw2[t * 16 + nn];
            #pragma unroll
            for (int mt = 0; mt < 2; ++mt)
                #pragma unroll
                for (int r = 0; r < 4; ++r)
                    part[mt][r] = fmaf(fmaxf(acc[mt][r] + b1t, 0.0f), w2t, part[mt][r]);
        }

        #pragma unroll
        for (int w = 1; w < 16; w <<= 1)
            #pragma unroll
            for (int mt = 0; mt < 2; ++mt)
                #pragma unroll
                for (int r = 0; r < 4; ++r)
                    part[mt][r] += __shfl_xor(part[mt][r], w, 64);

        const float bb = b2[0];
        if (nn == 0) {
            #pragma unroll
            for (int mt = 0; mt < 2; ++mt) {
                const int row = wb + mt * 16 + q * 4;
                if (row < n) {
                    float4 o4 = make_float4(part[mt][0] + bb, part[mt][1] + bb,
                                            part[mt][2] + bb, part[mt][3] + bb);
                    *(float4*)&o_out[row] = o4;
                }
            }
        }
        return;
    }

    // ================= SOLVE block =================
    {
        int mcnt = (b + 1) / 3; if (mcnt > nm) mcnt = nm;
        const int sidx = b - mcnt;
        const int h_   = tid & 3;
        const int i    = sidx * 64 + (tid >> 2);
        if (i >= n) return;

        const float sigma_sq = theta[0];
        const float phi      = theta[1];
        const float tau      = theta[2];
        const float tau_sq   = tau * sigma_sq;

        const float L2E = 1.44269504088896340736f;
        const float c1  = -phi * L2E;
        const float c0  = __builtin_amdgcn_logf(sigma_sq);

        const float sqrtEPS = __builtin_amdgcn_sqrtf(EPSF);
        const float diagA   = __builtin_amdgcn_exp2f(fmaf(sqrtEPS, c1, c0)) + tau_sq;
        const float diagB   = sigma_sq + tau;

        int idx[MM];
        const int4* nb4 = (const int4*)(nbr + (size_t)i * MM);
        #pragma unroll
        for (int k = 0; k < MM / 4; ++k) {
            int4 v = nb4[k];
            idx[4*k] = v.x; idx[4*k+1] = v.y; idx[4*k+2] = v.z; idx[4*k+3] = v.w;
        }

        float px[21], py[21];
        const float2* pos2 = (const float2*)pos;
        #pragma unroll
        for (int j = 0; j < MM; ++j) {
            float2 p = pos2[idx[j]];
            px[j] = p.x; py[j] = p.y;
        }
        {
            float2 p = pos2[i];
            px[20] = p.x; py[20] = p.y;
        }

        float cx[5], cy[5];
        #pragma unroll
        for (int j = 0; j < 5; ++j) {
            int cj = nbr[(size_t)i * MM + 4*j + h_];
            float2 p = pos2[cj];
            cx[j] = p.x; cy[j] = p.y;
        }

        // ---- build my slots + replicated col 20 ----
        float csx[81];
        #pragma unroll
        for (int j = 0; j < 5; ++j) {
            #pragma unroll
            for (int r = 0; r <= 4*j + 3; ++r) {
                float dx = px[r] - cx[j];
                float dy = py[r] - cy[j];
                float d  = __builtin_amdgcn_sqrtf(fmaf(dx, dx, fmaf(dy, dy, EPSF)));
                float v  = __builtin_amdgcn_exp2f(fmaf(d, c1, c0));
                v = (r == 4*j + h_) ? diagA : v;
                CSE(j, r) = v;
            }
        }
        #pragma unroll
        for (int r = 0; r < 20; ++r) {
            float dx = px[r] - px[20];
            float dy = py[r] - py[20];
            float d  = __builtin_amdgcn_sqrtf(fmaf(dx, dx, fmaf(dy, dy, EPSF)));
            C20(r)   = __builtin_amdgcn_exp2f(fmaf(d, c1, c0));
        }
        C20(20) = diagB;

        // ---- elimination: 5 phases x 4 rolled steps (no border vector) ----
        float pk[5], mv[5], mall[21], p20, pd;

        #pragma unroll 1
        for (int k = 0; k < 4; ++k) {
            switch (k) {
            SCASE(0,0) SCASE(1,0) SCASE(2,0) SCASE(3,0)
            default: break;
            }
            float rp = __builtin_amdgcn_rcpf(pd);
            rp = rp * (2.0f - pd * rp);
            #pragma unroll
            for (int j = 0; j < 5; ++j)
                mv[j] = (4*j + h_ > k) ? pk[j] * rp : 0.0f;
            GATH(0)  GATH(1)  GATH(2)  GATH(3)  GATH(4)  GATH(5)  GATH(6)
            GATH(7)  GATH(8)  GATH(9)  GATH(10) GATH(11) GATH(12) GATH(13)
            GATH(14) GATH(15) GATH(16) GATH(17) GATH(18) GATH(19)
            mall[20] = p20 * rp;
            #pragma unroll
            for (int j = 0; j < 5; ++j) {
                float pkj = pk[j];
                #pragma unroll
                for (int r = 0; r <= 4*j + 3; ++r)
                    CSE(j, r) = fmaf(-mall[r], pkj, CSE(j, r));
            }
            #pragma unroll
            for (int r = 0; r <= 20; ++r)
                C20(r) = fmaf(-mall[r], p20, C20(r));
        }

        #pragma unroll 1
        for (int k = 4; k < 8; ++k) {
            switch (k) {
            SCASE(4,1) SCASE(5,1) SCASE(6,1) SCASE(7,1)
            default: break;
            }
            float rp = __builtin_amdgcn_rcpf(pd);
            rp = rp * (2.0f - pd * rp);
            #pragma unroll
            for (int j = 1; j < 5; ++j)
                mv[j] = (4*j + h_ > k) ? pk[j] * rp : 0.0f;
            GATH(4)  GATH(5)  GATH(6)  GATH(7)  GATH(8)  GATH(9)  GATH(10)
            GATH(11) GATH(12) GATH(13) GATH(14) GATH(15) GATH(16) GATH(17)
            GATH(18) GATH(19)
            mall[20] = p20 * rp;
            #pragma unroll
            for (int j = 1; j < 5; ++j) {
                float pkj = pk[j];
                #pragma unroll
                for (int r = 4; r <= 4*j + 3; ++r)
                    CSE(j, r) = fmaf(-mall[r], pkj, CSE(j, r));
            }
            #pragma unroll
            for (int r = 4; r <= 20; ++r)
                C20(r) = fmaf(-mall[r], p20, C20(r));
        }

        #pragma unroll 1
        for (int k = 8; k < 12; ++k) {
            switch (k) {
            SCASE(8,2) SCASE(9,2) SCASE(10,2) SCASE(11,2)
            default: break;
            }
            float rp = __builtin_amdgcn_rcpf(pd);
            rp = rp * (2.0f - pd * rp);
            #pragma unroll
            for (int j = 2; j < 5; ++j)
                mv[j] = (4*j + h_ > k) ? pk[j] * rp : 0.0f;
            GATH(8)  GATH(9)  GATH(10) GATH(11) GATH(12) GATH(13) GATH(14)
            GATH(15) GATH(16) GATH(17) GATH(18) GATH(19)
            mall[20] = p20 * rp;
            #pragma unroll
            for (int j = 2; j < 5; ++j) {
                float pkj = pk[j];
                #pragma unroll
                for (int r = 8; r <= 4*j + 3; ++r)
                    CSE(j, r) = fmaf(-mall[r], pkj, CSE(j, r));
            }
            #pragma unroll
            for (int r = 8; r <= 20; ++r)
                C20(r) = fmaf(-mall[r], p20, C20(r));
        }

        #pragma unroll 1
        for (int k = 12; k < 16; ++k) {
            switch (k) {
            SCASE(12,3) SCASE(13,3) SCASE(14,3) SCASE(15,3)
            default: break;
            }
            float rp = __builtin_amdgcn_rcpf(pd);
            rp = rp * (2.0f - pd * rp);
            #pragma unroll
            for (int j = 3; j < 5; ++j)
                mv[j] = (4*j + h_ > k) ? pk[j] * rp : 0.0f;
            GATH(12) GATH(13) GATH(14) GATH(15) GATH(16) GATH(17) GATH(18)
            GATH(19)
            mall[20] = p20 * rp;
            #pragma unroll
            for (int j = 3; j < 5; ++j) {
                float pkj = pk[j];
                #pragma unroll
                for (int r = 12; r <= 4*j + 3; ++r)
                    CSE(j, r) = fmaf(-mall[r], pkj, CSE(j, r));
            }
            #pragma unroll
            for (int r = 12; r <= 20; ++r)
                C20(r) = fmaf(-mall[r], p20, C20(r));
        }

        #pragma unroll 1
        for (int k = 16; k < 20; ++k) {
            switch (k) {
            SCASE(16,4) SCASE(17,4) SCASE(18,4) SCASE(19,4)
            default: break;
            }
            float rp = __builtin_amdgcn_rcpf(pd);
            rp = rp * (2.0f - pd * rp);
            mv[4] = (16 + h_ > k) ? pk[4] * rp : 0.0f;
            GATH(16) GATH(17) GATH(18) GATH(19)
            mall[20] = p20 * rp;
            {
                float pkj = pk[4];
                #pragma unroll
                for (int r = 16; r <= 19; ++r)
                    CSE(4, r) = fmaf(-mall[r], pkj, CSE(4, r));
            }
            #pragma unroll
            for (int r = 16; r <= 20; ++r)
                C20(r) = fmaf(-mall[r], p20, C20(r));
        }

        // ---- back-substitution: U b = L^{-1}c, 20 straight-line steps ----
        float bl[5];
        BSTEP(19,5) BSTEP(18,4) BSTEP(17,4) BSTEP(16,4)
        BSTEP(15,4) BSTEP(14,3) BSTEP(13,3) BSTEP(12,3)
        BSTEP(11,3) BSTEP(10,2) BSTEP(9,2)  BSTEP(8,2)
        BSTEP(7,2)  BSTEP(6,1)  BSTEP(5,1)  BSTEP(4,1)
        BSTEP(3,1)  BSTEP(2,0)  BSTEP(1,0)  BSTEP(0,0)

        // ---- f, is; store weights; yd directly (y is an input) ----
        float f  = C20(20);
        float is = __builtin_amdgcn_rsqf(f);
        is = is * fmaf(-0.5f * f * is, is, 1.5f);

        float* wp = wis + (size_t)i * WSTR;
        #pragma unroll
        for (int j = 0; j < 5; ++j)
            wp[4*j + h_] = bl[j] * is;

        float sy = 0.0f;
        #pragma unroll
        for (int j = 0; j < 5; ++j) {
            int cj = nbr[(size_t)i * MM + 4*j + h_];   // L2-hot (read above)
            sy = fmaf(bl[j], y[cj], sy);
        }
        sy += __shfl_xor(sy, 1, 64);
        sy += __shfl_xor(sy, 2, 64);
        if (h_ == 0) {
            wp[20] = is;
            yd[i]  = (y[i] - sy) * is;
        }
    }
}

__global__ __launch_bounds__(256, 4)
void epilogue_od(const int*   __restrict__ nbr,
                 const float* __restrict__ o_in,
                 const float* __restrict__ wis,
                 float* __restrict__ od, int n)
{
    const int tid = threadIdx.x;
    const int h_  = tid & 3;
    const int i   = blockIdx.x * 64 + (tid >> 2);     // 4 lanes per node
    if (i >= n) return;

    const float* wp = wis + (size_t)i * WSTR;
    float so = 0.0f;
    #pragma unroll
    for (int j = 0; j < 5; ++j) {
        int cj = nbr[(size_t)i * MM + 4*j + h_];
        so = fmaf(wp[4*j + h_], o_in[cj], so);
    }
    so += __shfl_xor(so, 1, 64);
    so += __shfl_xor(so, 2, 64);
    if (h_ == 0) {
        float is = wp[20];
        od[i] = fmaf(is, o_in[i], -so);
    }
}

extern "C" void kernel_launch(void* const* d_in, const int* in_sizes, int n_in,
                              void* d_out, int out_size, void* d_ws, size_t ws_size,
                              hipStream_t stream)
{
    const float* x     = (const float*)d_in[0];
    const float* pos   = (const float*)d_in[1];
    const float* y     = (const float*)d_in[2];
    const int*   nbr   = (const int*)  d_in[3];
    const float* theta = (const float*)d_in[4];
    const float* w1    = (const float*)d_in[5];
    const float* b1    = (const float*)d_in[6];
    const float* w2    = (const float*)d_in[7];
    const float* b2    = (const float*)d_in[8];

    const int n = in_sizes[2];                 // N
    float* out = (float*)d_out;
    float* yd = out;
    float* od = out + (size_t)n;
    float* oo = out + 2 * (size_t)n;
    float* wis = (float*)d_ws;                 // n * 24 floats = 19.2 MB

    const int nm = (n + 127) / 128;            // mlp blocks (128 nodes each)
    const int ns = (n + 63) / 64;              // solve blocks (64 nodes each)
    fused_kernel<<<nm + ns, 256, 0, stream>>>(x, w1, b1, w2, b2,
                                              pos, nbr, theta, y,
                                              oo, wis, yd, n, nm);
    epilogue_od<<<(n + 63) / 64, 256, 0, stream>>>(nbr, oo, wis, od, n);
}